// Round 12
// baseline (100.948 us; speedup 1.0000x reference)
//
#include <hip/hip_runtime.h>

#define NS 128
#define NRAYS 8192

typedef unsigned short u16;
typedef unsigned int   u32;
typedef unsigned short u16x8 __attribute__((ext_vector_type(8)));
typedef __bf16 b16x8 __attribute__((ext_vector_type(8)));
typedef float f32x4 __attribute__((ext_vector_type(4)));
typedef _Float16 h16x2 __attribute__((ext_vector_type(2)));
typedef unsigned int u32x4 __attribute__((ext_vector_type(4)));
typedef unsigned int u32x2 __attribute__((ext_vector_type(2)));
typedef float f32x2u __attribute__((ext_vector_type(2), aligned(4)));

__device__ __forceinline__ float clampf(float x, float lo, float hi) {
    return fminf(fmaxf(x, lo), hi);
}

__device__ __forceinline__ u16 f2bf(float f) {
    return __builtin_bit_cast(u16, (__bf16)f);
}

// pack two f32 -> bf16 pair in one u32 (lo in bits 0-15)
__device__ __forceinline__ u32 pk2bf(float lo, float hi) {
    return (u32)f2bf(lo) | ((u32)f2bf(hi) << 16);
}

__device__ __forceinline__ u32 pkh(float a, float b) {
    h16x2 v; v[0] = (_Float16)a; v[1] = (_Float16)b;
    return __builtin_bit_cast(u32, v);
}
__device__ __forceinline__ float2 uph(u32 u) {
    h16x2 v = __builtin_bit_cast(h16x2, u);
    return make_float2((float)v[0], (float)v[1]);
}

__device__ __forceinline__ f32x4 mfma_bf16(u16x8 a, u16x8 b, f32x4 c) {
    return __builtin_amdgcn_mfma_f32_16x16x32_bf16(
        __builtin_bit_cast(b16x8, a), __builtin_bit_cast(b16x8, b), c, 0, 0, 0);
}

// swizzled u16-index into a [16][64] tile stored [sample][dim]
#define TSW(n, k) ((((n) * 64) + (k)) ^ (((n) & 7) << 3))

__device__ __forceinline__ void plane_interp(const float* __restrict__ g,
                                             float ca, float cb, float o[3]) {
    float pa = clampf((ca + 1.f) * (0.5f * 127.f), 0.f, 127.f);
    float pb = clampf((cb + 1.f) * (0.5f * 127.f), 0.f, 127.f);
    int la = (int)pa; if (la > 126) la = 126;
    int lb = (int)pb; if (lb > 126) lb = 126;
    float fa = pa - (float)la, fb = pb - (float)lb;
    const float* p = g + la * 128 + lb;
#pragma unroll
    for (int c = 0; c < 3; ++c) {
        const float* q = p + c * 16384;
        f32x2u q0 = *(const f32x2u*)q;
        f32x2u q1 = *(const f32x2u*)(q + 128);
        float top = fmaf(q0[1] - q0[0], fb, q0[0]);
        float bot = fmaf(q1[1] - q1[0], fb, q1[0]);
        o[c] = fmaf(bot - top, fa, top);
    }
}

// ---- prep: pack weight A-fragments (bf16, per-lane layout) into workspace ----
// AWc1' rows: [0]=0, [1..15]=wc1 so-rows, [16..18]=wc1 dir-rows, [19]=bc1 (bias
// row, pairs with cin' row19 == 1.0), [20..31]=0.
// layout (u16x8 units): [0,256) AW1 (nb*64+lane), [256,512) AWc1',
//                       [512,640) AW2 (ks*64+lane), [640,768) AWc2
__global__ __launch_bounds__(256)
void prep_weights(const float* __restrict__ w1, const float* __restrict__ wc1,
                  const float* __restrict__ w2, const float* __restrict__ wc2,
                  const float* __restrict__ bc1,
                  u16* __restrict__ wsb)
{
    int idx = blockIdx.x * 256 + threadIdx.x;   // 0..6143
    if (idx >= 6144) return;
    int lane = (idx >> 3) & 63;
    int j = idx & 7;
    int c16 = lane & 15, kg = lane >> 4;
    float v;
    if (idx < 2048) {                       // AW1
        int nb = idx >> 9;
        int k = kg * 8 + j;
        v = w1[k * 64 + nb * 16 + c16];
    } else if (idx < 4096) {                // AWc1' (permuted rows + bias row)
        int nb = (idx - 2048) >> 9;
        int k = kg * 8 + j;
        if (k == 0)       v = 0.f;
        else if (k < 16)  v = wc1[(k + 2) * 64 + nb * 16 + c16];
        else if (k < 19)  v = wc1[(k - 16) * 64 + nb * 16 + c16];
        else if (k == 19) v = bc1[nb * 16 + c16];
        else              v = 0.f;
    } else if (idx < 5120) {                // AW2
        int ks = (idx - 4096) >> 9;
        int k = ks * 32 + kg * 8 + j;
        v = w2[k * 16 + c16];
    } else {                                // AWc2 (M padded 3->16)
        int ks = (idx - 5120) >> 9;
        int k = ks * 32 + kg * 8 + j;
        v = (c16 < 3) ? wc2[k * 3 + c16] : 0.f;
    }
    wsb[idx] = f2bf(v);
}

// block = 4 rays, 4 waves, 1 wave = 1 ray. Chunks processed in PAIRS (2-wide
// ILP): two independent GEMM/LDS ladders per iteration so the scheduler can
// interleave them and hide the ds_write->ds_read->MFMA chain latency.
// Barrier-free. Swapped-operand GEMMs (weights = A-operand). b1 bias from
// per-wave LDS; bc1 folded into AWc1' row 19 (cin' row 19 = 1.0).
__global__ __launch_bounds__(256)
void nerf_mfma(const float* __restrict__ rays_o,
               const float* __restrict__ rays_d,
               const float* __restrict__ bg_color,
               const float* __restrict__ plane01,
               const float* __restrict__ plane02,
               const float* __restrict__ plane12,
               const float* __restrict__ features,
               const float* __restrict__ w1, const float* __restrict__ b1,
               const float* __restrict__ w2, const float* __restrict__ b2,
               const float* __restrict__ wc1, const float* __restrict__ bc1,
               const float* __restrict__ wc2, const float* __restrict__ bc2,
               const float* __restrict__ aabb,
               float* __restrict__ out,
               const u16* __restrict__ wsb, int use_ws)
{
    __shared__ __align__(16) u32x4 s_cw[4][128];        // trilinear corner weights
    __shared__ u32   s_fb[4][128];                      // cell base offsets
    __shared__ __align__(16) u16  s_tile[4][2][16 * 64];// per-wave, 2 slots (A/B)
    __shared__ __align__(16) float s_b1[4][64];         // per-wave b1 copy
    __shared__ float s_tau[4][128];
    __shared__ float s_rgb[4][3][128];

    const int tid  = threadIdx.x;
    const int wv   = tid >> 6;
    const int lane = tid & 63;
    const int c16  = lane & 15;
    const int kg   = lane >> 4;
    const int ray  = blockIdx.x * 4 + wv;
    const int sA   = c16 + 16 * ((2 * kg) & 3);
    const int sB   = c16 + 16 * ((2 * kg + 1) & 3);

    // ---- weight A-fragments (VGPR-resident) ----
    u16x8 AW1[4], AWc1[4], AW2[2], AWc2[2];
    if (use_ws) {
        const u16x8* wf = (const u16x8*)wsb;
#pragma unroll
        for (int nb = 0; nb < 4; ++nb) {
            AW1[nb]  = wf[nb * 64 + lane];
            AWc1[nb] = wf[256 + nb * 64 + lane];
        }
#pragma unroll
        for (int ks = 0; ks < 2; ++ks) {
            AW2[ks]  = wf[512 + ks * 64 + lane];
            AWc2[ks] = wf[640 + ks * 64 + lane];
        }
    } else {
#pragma unroll
        for (int nb = 0; nb < 4; ++nb)
#pragma unroll
            for (int j = 0; j < 8; ++j) {
                int k = kg * 8 + j;
                AW1[nb][j] = f2bf(w1[k * 64 + nb * 16 + c16]);
                float v;
                if (k == 0)       v = 0.f;
                else if (k < 16)  v = wc1[(k + 2) * 64 + nb * 16 + c16];
                else if (k < 19)  v = wc1[(k - 16) * 64 + nb * 16 + c16];
                else if (k == 19) v = bc1[nb * 16 + c16];
                else              v = 0.f;
                AWc1[nb][j] = f2bf(v);
            }
#pragma unroll
        for (int ks = 0; ks < 2; ++ks)
#pragma unroll
            for (int j = 0; j < 8; ++j) {
                int k = ks * 32 + kg * 8 + j;
                AW2[ks][j]  = f2bf(w2[k * 16 + c16]);
                AWc2[ks][j] = f2bf(c16 < 3 ? wc2[k * 3 + c16] : 0.f);
            }
    }
    // b1 -> per-wave LDS (C-init read per chunk)
    s_b1[wv][lane] = b1[lane];
    f32x4 b2v4 = *(const f32x4*)(b2 + kg * 4);
    f32x4 bc2v4; bc2v4[0] = bc2v4[1] = bc2v4[2] = bc2v4[3] = 0.f;
    if (kg == 0) { bc2v4[0] = bc2[0]; bc2v4[1] = bc2[1]; bc2v4[2] = bc2[2]; }
    f32x4 zz; zz[0] = zz[1] = zz[2] = zz[3] = 0.f;

    // ---- per-ray setup ----
    float ox = rays_o[ray * 3 + 0], oy = rays_o[ray * 3 + 1], oz = rays_o[ray * 3 + 2];
    float dx = rays_d[ray * 3 + 0], dy = rays_d[ray * 3 + 1], dz = rays_d[ray * 3 + 2];
    float rn = rsqrtf(dx * dx + dy * dy + dz * dz);
    dx *= rn; dy *= rn; dz *= rn;

    float lo0 = aabb[0], lo1 = aabb[1], lo2 = aabb[2];
    float hi0 = aabb[3], hi1 = aabb[4], hi2 = aabb[5];

    float invx = 1.f / dx, invy = 1.f / dy, invz = 1.f / dz;
    float tx0 = (lo0 - ox) * invx, tx1 = (hi0 - ox) * invx;
    float ty0 = (lo1 - oy) * invy, ty1 = (hi1 - oy) * invy;
    float tz0 = (lo2 - oz) * invz, tz1 = (hi2 - oz) * invz;
    float tnear = fmaxf(fmaxf(fminf(tx0, tx1), fminf(ty0, ty1)), fminf(tz0, tz1));
    tnear = fmaxf(tnear, 0.f);
    float tfar = fminf(fminf(fmaxf(tx0, tx1), fmaxf(ty0, ty1)), fmaxf(tz0, tz1));
    tfar = fmaxf(tfar, tnear);
    float delta = (tfar - tnear) * (1.f / (float)NS);

    // dir constants for cin' rows 16..18 + bias row 19 (kg==2 k-slice)
    const u32 dir01 = pk2bf(dx, dy);
    const u32 dir2b = pk2bf(dz, 1.0f);

    // ---- coordinate phase: this wave, 2 samples per lane ----
#pragma unroll
    for (int i = 0; i < 2; ++i) {
        int s = i * 64 + lane;
        float t = tnear + delta * ((float)s + 0.5f);
        float px = ox + dx * t, py = oy + dy * t, pz = oz + dz * t;
        px = (px - lo0) * (2.f / (hi0 - lo0)) - 1.f;
        py = (py - lo1) * (2.f / (hi1 - lo1)) - 1.f;
        pz = (pz - lo2) * (2.f / (hi2 - lo2)) - 1.f;

        float p01[3], p02[3], p12[3];
        plane_interp(plane01, px, py, p01);
        plane_interp(plane02, px, pz, p02);
        plane_interp(plane12, py, pz, p12);
        float gx = p01[0] * p02[0] * p12[0];
        float gy = p01[1] * p02[1] * p12[1];
        float gz = p01[2] * p02[2] * p12[2];

        float qx = clampf((gx + 1.f) * (0.5f * 63.f), 0.f, 63.f);
        float qy = clampf((gy + 1.f) * (0.5f * 63.f), 0.f, 63.f);
        float qz = clampf((gz + 1.f) * (0.5f * 63.f), 0.f, 63.f);
        int ixg = (int)qx; if (ixg > 62) ixg = 62;
        int iyg = (int)qy; if (iyg > 62) iyg = 62;
        int izg = (int)qz; if (izg > 62) izg = 62;
        float fx = qx - (float)ixg, fy = qy - (float)iyg, fz = qz - (float)izg;
        float wx0 = 1.f - fx, wy0 = 1.f - fy, wz0 = 1.f - fz;
        u32x4 cw;
        cw[0] = pkh(wx0 * wy0 * wz0, wx0 * wy0 * fz);
        cw[1] = pkh(wx0 * fy  * wz0, wx0 * fy  * fz);
        cw[2] = pkh(fx  * wy0 * wz0, fx  * wy0 * fz);
        cw[3] = pkh(fx  * fy  * wz0, fx  * fy  * fz);
        s_cw[wv][s] = cw;
        s_fb[wv][s] = (u32)(ixg * 4096 + iyg * 64 + izg);
    }

    // relu C-regs, pack, b64-store to swizzled tile slot SL
#define RELUSTORE(ACC, NB, SL) {                                       \
        u32x2 wr_;                                                     \
        wr_[0] = pk2bf(fmaxf((ACC)[0], 0.f), fmaxf((ACC)[1], 0.f));    \
        wr_[1] = pk2bf(fmaxf((ACC)[2], 0.f), fmaxf((ACC)[3], 0.f));    \
        *(u32x2*)&s_tile[wv][SL][TSW(c16, (NB) * 16 + kg * 4)] = wr_; }

    // gather + trilinear combine for one chunk -> u16x8 B-operand
#define GATHER(A1OUT, CWP, FBV) {                                      \
        float2 w0p = uph((CWP)[0]);                                    \
        float2 w1p = uph((CWP)[1]);                                    \
        float2 w2p = uph((CWP)[2]);                                    \
        float2 w3p = uph((CWP)[3]);                                    \
        const float* fbase_ = features + (FBV);                        \
        u32x4 a1v_;                                                    \
        _Pragma("unroll")                                              \
        for (int jj = 0; jj < 4; ++jj) {                               \
            float vv_[2];                                              \
            _Pragma("unroll")                                          \
            for (int h = 0; h < 2; ++h) {                              \
                const float* f_ = fbase_ + (size_t)(kg * 8 + jj * 2 + h) * 262144; \
                f32x2u q0 = *(const f32x2u*)(f_);                      \
                f32x2u q1 = *(const f32x2u*)(f_ + 64);                 \
                f32x2u q2 = *(const f32x2u*)(f_ + 4096);               \
                f32x2u q3 = *(const f32x2u*)(f_ + 4160);               \
                vv_[h] = fmaf(w0p.x, q0[0], fmaf(w0p.y, q0[1],         \
                         fmaf(w1p.x, q1[0], fmaf(w1p.y, q1[1],         \
                         fmaf(w2p.x, q2[0], fmaf(w2p.y, q2[1],         \
                         fmaf(w3p.x, q3[0], w3p.y * q3[1])))))));      \
            }                                                          \
            a1v_[jj] = pk2bf(vv_[0], vv_[1]);                          \
        }                                                              \
        A1OUT = __builtin_bit_cast(u16x8, a1v_); }

    // ---- 4 pair-iterations, 2 chunks side by side ----
#pragma unroll 1
    for (int cp = 0; cp < 4; ++cp) {
        const int cA = cp * 2, cB = cp * 2 + 1;
        u32x4 cwA = s_cw[wv][cA * 16 + c16];
        u32   fbA = s_fb[wv][cA * 16 + c16];
        u32x4 cwB = s_cw[wv][cB * 16 + c16];
        u32   fbB = s_fb[wv][cB * 16 + c16];

        // --- chunk A: gather -> GEMM1 -> retire to tile slot 0 ---
        u16x8 a1A; GATHER(a1A, cwA, fbA);
        {
            f32x4 g0 = mfma_bf16(AW1[0], a1A, *(const f32x4*)&s_b1[wv][0 * 16 + kg * 4]);
            f32x4 g1 = mfma_bf16(AW1[1], a1A, *(const f32x4*)&s_b1[wv][1 * 16 + kg * 4]);
            f32x4 g2 = mfma_bf16(AW1[2], a1A, *(const f32x4*)&s_b1[wv][2 * 16 + kg * 4]);
            f32x4 g3 = mfma_bf16(AW1[3], a1A, *(const f32x4*)&s_b1[wv][3 * 16 + kg * 4]);
            RELUSTORE(g0, 0, 0); RELUSTORE(g1, 1, 0);
            RELUSTORE(g2, 2, 0); RELUSTORE(g3, 3, 0);
        }
        // --- chunk B: gather -> GEMM1 -> retire to tile slot 1 ---
        u16x8 a1B; GATHER(a1B, cwB, fbB);
        {
            f32x4 g0 = mfma_bf16(AW1[0], a1B, *(const f32x4*)&s_b1[wv][0 * 16 + kg * 4]);
            f32x4 g1 = mfma_bf16(AW1[1], a1B, *(const f32x4*)&s_b1[wv][1 * 16 + kg * 4]);
            f32x4 g2 = mfma_bf16(AW1[2], a1B, *(const f32x4*)&s_b1[wv][2 * 16 + kg * 4]);
            f32x4 g3 = mfma_bf16(AW1[3], a1B, *(const f32x4*)&s_b1[wv][3 * 16 + kg * 4]);
            RELUSTORE(g0, 0, 1); RELUSTORE(g1, 1, 1);
            RELUSTORE(g2, 2, 1); RELUSTORE(g3, 3, 1);
        }

        // --- GEMM2 both (independent ladders) ---
        u16x8 B2A_0 = *(const u16x8*)&s_tile[wv][0][TSW(c16, kg * 8)];
        u16x8 B2A_1 = *(const u16x8*)&s_tile[wv][0][TSW(c16, 32 + kg * 8)];
        u16x8 B2B_0 = *(const u16x8*)&s_tile[wv][1][TSW(c16, kg * 8)];
        u16x8 B2B_1 = *(const u16x8*)&s_tile[wv][1][TSW(c16, 32 + kg * 8)];
        f32x4 soA = mfma_bf16(AW2[0], B2A_0, b2v4);
        f32x4 soB = mfma_bf16(AW2[0], B2B_0, b2v4);
        soA = mfma_bf16(AW2[1], B2A_1, soA);
        soB = mfma_bf16(AW2[1], B2B_1, soB);

        if (kg == 0) {
            s_tau[wv][cA * 16 + c16] = __expf(clampf(soA[0], -15.f, 15.f)) * delta;
            s_tau[wv][cB * 16 + c16] = __expf(clampf(soB[0], -15.f, 15.f)) * delta;
        }

        // --- cin' fragments via shuffles, both ---
        u32 QA0 = pk2bf(soA[0], soA[1]);
        u32 QA1 = pk2bf(soA[2], soA[3]);
        u32 QB0 = pk2bf(soB[0], soB[1]);
        u32 QB1 = pk2bf(soB[2], soB[3]);
        u32x4 ctA, ctB;
        ctA[0] = (u32)__shfl((int)QA0, sA);
        ctA[1] = (u32)__shfl((int)QA1, sA);
        ctA[2] = (u32)__shfl((int)QA0, sB);
        ctA[3] = (u32)__shfl((int)QA1, sB);
        ctB[0] = (u32)__shfl((int)QB0, sA);
        ctB[1] = (u32)__shfl((int)QB1, sA);
        ctB[2] = (u32)__shfl((int)QB0, sB);
        ctB[3] = (u32)__shfl((int)QB1, sB);
        if (kg == 2) {
            ctA[0] = dir01; ctA[1] = dir2b; ctA[2] = 0u; ctA[3] = 0u;
            ctB[0] = dir01; ctB[1] = dir2b; ctB[2] = 0u; ctB[3] = 0u;
        }
        if (kg == 3) {
            ctA[0] = 0u; ctA[1] = 0u; ctA[2] = 0u; ctA[3] = 0u;
            ctB[0] = 0u; ctB[1] = 0u; ctB[2] = 0u; ctB[3] = 0u;
        }
        u16x8 bcinA = __builtin_bit_cast(u16x8, ctA);
        u16x8 bcinB = __builtin_bit_cast(u16x8, ctB);

        // --- GEMM3 A -> retire, GEMM3 B -> retire ---
        {
            f32x4 h0 = mfma_bf16(AWc1[0], bcinA, zz);
            f32x4 h1 = mfma_bf16(AWc1[1], bcinA, zz);
            f32x4 h2 = mfma_bf16(AWc1[2], bcinA, zz);
            f32x4 h3 = mfma_bf16(AWc1[3], bcinA, zz);
            RELUSTORE(h0, 0, 0); RELUSTORE(h1, 1, 0);
            RELUSTORE(h2, 2, 0); RELUSTORE(h3, 3, 0);
        }
        {
            f32x4 h0 = mfma_bf16(AWc1[0], bcinB, zz);
            f32x4 h1 = mfma_bf16(AWc1[1], bcinB, zz);
            f32x4 h2 = mfma_bf16(AWc1[2], bcinB, zz);
            f32x4 h3 = mfma_bf16(AWc1[3], bcinB, zz);
            RELUSTORE(h0, 0, 1); RELUSTORE(h1, 1, 1);
            RELUSTORE(h2, 2, 1); RELUSTORE(h3, 3, 1);
        }

        // --- GEMM4 both ---
        u16x8 B4A_0 = *(const u16x8*)&s_tile[wv][0][TSW(c16, kg * 8)];
        u16x8 B4A_1 = *(const u16x8*)&s_tile[wv][0][TSW(c16, 32 + kg * 8)];
        u16x8 B4B_0 = *(const u16x8*)&s_tile[wv][1][TSW(c16, kg * 8)];
        u16x8 B4B_1 = *(const u16x8*)&s_tile[wv][1][TSW(c16, 32 + kg * 8)];
        f32x4 ccA = mfma_bf16(AWc2[0], B4A_0, bc2v4);
        f32x4 ccB = mfma_bf16(AWc2[0], B4B_0, bc2v4);
        ccA = mfma_bf16(AWc2[1], B4A_1, ccA);
        ccB = mfma_bf16(AWc2[1], B4B_1, ccB);

        if (kg == 0) {
            int siA = cA * 16 + c16, siB = cB * 16 + c16;
            s_rgb[wv][0][siA] = 1.f / (1.f + __expf(-ccA[0]));
            s_rgb[wv][1][siA] = 1.f / (1.f + __expf(-ccA[1]));
            s_rgb[wv][2][siA] = 1.f / (1.f + __expf(-ccA[2]));
            s_rgb[wv][0][siB] = 1.f / (1.f + __expf(-ccB[0]));
            s_rgb[wv][1][siB] = 1.f / (1.f + __expf(-ccB[1]));
            s_rgb[wv][2][siB] = 1.f / (1.f + __expf(-ccB[2]));
        }
    }
#undef RELUSTORE
#undef GATHER

    // ---- per-ray exponential integration (2 samples per lane) ----
    float t0 = s_tau[wv][lane];
    float t1 = s_tau[wv][64 + lane];
    float x0 = t0, x1 = t1;
#pragma unroll
    for (int off = 1; off < 64; off <<= 1) {
        float y = __shfl_up(x0, off);
        if (lane >= off) x0 += y;
    }
    float tot0 = __shfl(x0, 63);
#pragma unroll
    for (int off = 1; off < 64; off <<= 1) {
        float y = __shfl_up(x1, off);
        if (lane >= off) x1 += y;
    }
    x1 += tot0;

    float w0 = __expf(t0 - x0) * (1.f - __expf(-t0));
    float w1s = __expf(t1 - x1) * (1.f - __expf(-t1));

    float v0 = w0 * s_rgb[wv][0][lane] + w1s * s_rgb[wv][0][64 + lane];
    float v1 = w0 * s_rgb[wv][1][lane] + w1s * s_rgb[wv][1][64 + lane];
    float v2 = w0 * s_rgb[wv][2][lane] + w1s * s_rgb[wv][2][64 + lane];
    float v3 = w0 + w1s;
#pragma unroll
    for (int off = 32; off; off >>= 1) {
        v0 += __shfl_xor(v0, off);
        v1 += __shfl_xor(v1, off);
        v2 += __shfl_xor(v2, off);
        v3 += __shfl_xor(v3, off);
    }
    if (lane == 0) {
        float bg = bg_color[0];
        out[ray * 3 + 0] = v0 + (1.f - v3) * bg;
        out[ray * 3 + 1] = v1 + (1.f - v3) * bg;
        out[ray * 3 + 2] = v2 + (1.f - v3) * bg;
    }
}

extern "C" void kernel_launch(void* const* d_in, const int* in_sizes, int n_in,
                              void* d_out, int out_size, void* d_ws, size_t ws_size,
                              hipStream_t stream) {
    const float* rays_o  = (const float*)d_in[0];
    const float* rays_d  = (const float*)d_in[1];
    const float* bg      = (const float*)d_in[2];
    const float* p01     = (const float*)d_in[3];
    const float* p02     = (const float*)d_in[4];
    const float* p12     = (const float*)d_in[5];
    const float* feats   = (const float*)d_in[6];
    const float* w1      = (const float*)d_in[7];
    const float* b1      = (const float*)d_in[8];
    const float* w2      = (const float*)d_in[9];
    const float* b2      = (const float*)d_in[10];
    const float* wc1     = (const float*)d_in[11];
    const float* bc1     = (const float*)d_in[12];
    const float* wc2     = (const float*)d_in[13];
    const float* bc2     = (const float*)d_in[14];
    const float* aabb    = (const float*)d_in[15];
    float* out = (float*)d_out;

    const int use_ws = (ws_size >= 6144 * sizeof(u16)) ? 1 : 0;
    u16* wsb = (u16*)d_ws;
    if (use_ws) {
        prep_weights<<<24, 256, 0, stream>>>(w1, wc1, w2, wc2, bc1, wsb);
    }
    nerf_mfma<<<NRAYS / 4, 256, 0, stream>>>(rays_o, rays_d, bg, p01, p02, p12, feats,
                                             w1, b1, w2, b2, wc1, bc1, wc2, bc2, aabb, out,
                                             wsb, use_ws);
}

// Round 13
// 93.825 us; speedup vs baseline: 1.0759x; 1.0759x over previous
//
#include <hip/hip_runtime.h>

#define NS 128
#define NRAYS 8192

typedef unsigned short u16;
typedef unsigned int   u32;
typedef unsigned short u16x8 __attribute__((ext_vector_type(8)));
typedef __bf16 b16x8 __attribute__((ext_vector_type(8)));
typedef float f32x4 __attribute__((ext_vector_type(4)));
typedef _Float16 h16x2 __attribute__((ext_vector_type(2)));
typedef unsigned int u32x4 __attribute__((ext_vector_type(4)));
typedef unsigned int u32x2 __attribute__((ext_vector_type(2)));
typedef float f32x2u __attribute__((ext_vector_type(2), aligned(4)));

__device__ __forceinline__ float clampf(float x, float lo, float hi) {
    return fminf(fmaxf(x, lo), hi);
}

__device__ __forceinline__ u16 f2bf(float f) {
    return __builtin_bit_cast(u16, (__bf16)f);
}

// pack two f32 -> bf16 pair in one u32 (lo in bits 0-15)
__device__ __forceinline__ u32 pk2bf(float lo, float hi) {
    return (u32)f2bf(lo) | ((u32)f2bf(hi) << 16);
}

__device__ __forceinline__ u32 pkh(float a, float b) {
    h16x2 v; v[0] = (_Float16)a; v[1] = (_Float16)b;
    return __builtin_bit_cast(u32, v);
}
__device__ __forceinline__ float2 uph(u32 u) {
    h16x2 v = __builtin_bit_cast(h16x2, u);
    return make_float2((float)v[0], (float)v[1]);
}

__device__ __forceinline__ f32x4 mfma_bf16(u16x8 a, u16x8 b, f32x4 c) {
    return __builtin_amdgcn_mfma_f32_16x16x32_bf16(
        __builtin_bit_cast(b16x8, a), __builtin_bit_cast(b16x8, b), c, 0, 0, 0);
}

// swizzled u16-index into a [16][64] tile stored [sample][dim]
#define TSW(n, k) ((((n) * 64) + (k)) ^ (((n) & 7) << 3))

__device__ __forceinline__ void plane_interp(const float* __restrict__ g,
                                             float ca, float cb, float o[3]) {
    float pa = clampf((ca + 1.f) * (0.5f * 127.f), 0.f, 127.f);
    float pb = clampf((cb + 1.f) * (0.5f * 127.f), 0.f, 127.f);
    int la = (int)pa; if (la > 126) la = 126;
    int lb = (int)pb; if (lb > 126) lb = 126;
    float fa = pa - (float)la, fb = pb - (float)lb;
    const float* p = g + la * 128 + lb;
#pragma unroll
    for (int c = 0; c < 3; ++c) {
        const float* q = p + c * 16384;
        f32x2u q0 = *(const f32x2u*)q;
        f32x2u q1 = *(const f32x2u*)(q + 128);
        float top = fmaf(q0[1] - q0[0], fb, q0[0]);
        float bot = fmaf(q1[1] - q1[0], fb, q1[0]);
        o[c] = fmaf(bot - top, fa, top);
    }
}

// ---- prep: pack weight A-fragments (bf16, per-lane layout) into workspace ----
// AWc1' rows: [0]=0, [1..15]=wc1 so-rows, [16..18]=wc1 dir-rows, [19]=bc1 (bias
// row, pairs with cin' row19 == 1.0), [20..31]=0.
// layout (u16x8 units): [0,256) AW1 (nb*64+lane), [256,512) AWc1',
//                       [512,640) AW2 (ks*64+lane), [640,768) AWc2
__global__ __launch_bounds__(256)
void prep_weights(const float* __restrict__ w1, const float* __restrict__ wc1,
                  const float* __restrict__ w2, const float* __restrict__ wc2,
                  const float* __restrict__ bc1,
                  u16* __restrict__ wsb)
{
    int idx = blockIdx.x * 256 + threadIdx.x;   // 0..6143
    if (idx >= 6144) return;
    int lane = (idx >> 3) & 63;
    int j = idx & 7;
    int c16 = lane & 15, kg = lane >> 4;
    float v;
    if (idx < 2048) {                       // AW1
        int nb = idx >> 9;
        int k = kg * 8 + j;
        v = w1[k * 64 + nb * 16 + c16];
    } else if (idx < 4096) {                // AWc1' (permuted rows + bias row)
        int nb = (idx - 2048) >> 9;
        int k = kg * 8 + j;
        if (k == 0)       v = 0.f;
        else if (k < 16)  v = wc1[(k + 2) * 64 + nb * 16 + c16];
        else if (k < 19)  v = wc1[(k - 16) * 64 + nb * 16 + c16];
        else if (k == 19) v = bc1[nb * 16 + c16];
        else              v = 0.f;
    } else if (idx < 5120) {                // AW2
        int ks = (idx - 4096) >> 9;
        int k = ks * 32 + kg * 8 + j;
        v = w2[k * 16 + c16];
    } else {                                // AWc2 (M padded 3->16)
        int ks = (idx - 5120) >> 9;
        int k = ks * 32 + kg * 8 + j;
        v = (c16 < 3) ? wc2[k * 3 + c16] : 0.f;
    }
    wsb[idx] = f2bf(v);
}

// block = 4 rays, 4 waves, 1 wave = 1 ray, 8 chunks of 16 samples per wave.
// Weight fragments + biases live in BLOCK-SHARED LDS (read per MFMA via
// ds_read_b128, uniform base + lane*16B) to cut the per-wave register
// footprint below the residency cliff. Swapped-operand GEMMs; bc1 folded into
// AWc1' row 19 (cin' row 19 = 1.0). One __syncthreads after staging.
__global__ __launch_bounds__(256)
void nerf_mfma(const float* __restrict__ rays_o,
               const float* __restrict__ rays_d,
               const float* __restrict__ bg_color,
               const float* __restrict__ plane01,
               const float* __restrict__ plane02,
               const float* __restrict__ plane12,
               const float* __restrict__ features,
               const float* __restrict__ w1, const float* __restrict__ b1,
               const float* __restrict__ w2, const float* __restrict__ b2,
               const float* __restrict__ wc1, const float* __restrict__ bc1,
               const float* __restrict__ wc2, const float* __restrict__ bc2,
               const float* __restrict__ aabb,
               float* __restrict__ out,
               const u16* __restrict__ wsb, int use_ws)
{
    __shared__ __align__(16) u16x8 s_wfrag[768];        // block-shared weights (12.3 KB)
    __shared__ __align__(16) float s_bias[96];          // b1[64], b2[16], bc2pad[16]
    __shared__ __align__(16) u32x4 s_cw[4][128];        // trilinear corner weights
    __shared__ u32   s_fb[4][128];                      // cell base offsets
    __shared__ __align__(16) u16  s_tile[4][16 * 64];   // per-wave transpose tile
    __shared__ float s_tau[4][128];
    __shared__ float s_rgb[4][3][128];

    const int tid  = threadIdx.x;
    const int wv   = tid >> 6;
    const int lane = tid & 63;
    const int c16  = lane & 15;
    const int kg   = lane >> 4;
    const int ray  = blockIdx.x * 4 + wv;
    const int sA   = c16 + 16 * ((2 * kg) & 3);
    const int sB   = c16 + 16 * ((2 * kg + 1) & 3);

    // ---- stage weights + biases to block-shared LDS ----
    if (use_ws) {
        const u16x8* wf = (const u16x8*)wsb;
#pragma unroll
        for (int i = 0; i < 3; ++i) s_wfrag[tid + 256 * i] = wf[tid + 256 * i];
    } else if (wv == 0) {
#pragma unroll
        for (int nb = 0; nb < 4; ++nb) {
            u16x8 a, c;
#pragma unroll
            for (int j = 0; j < 8; ++j) {
                int k = kg * 8 + j;
                a[j] = f2bf(w1[k * 64 + nb * 16 + c16]);
                float v;
                if (k == 0)       v = 0.f;
                else if (k < 16)  v = wc1[(k + 2) * 64 + nb * 16 + c16];
                else if (k < 19)  v = wc1[(k - 16) * 64 + nb * 16 + c16];
                else if (k == 19) v = bc1[nb * 16 + c16];
                else              v = 0.f;
                c[j] = f2bf(v);
            }
            s_wfrag[nb * 64 + lane] = a;
            s_wfrag[256 + nb * 64 + lane] = c;
        }
#pragma unroll
        for (int ks = 0; ks < 2; ++ks) {
            u16x8 a, c;
#pragma unroll
            for (int j = 0; j < 8; ++j) {
                int k = ks * 32 + kg * 8 + j;
                a[j] = f2bf(w2[k * 16 + c16]);
                c[j] = f2bf(c16 < 3 ? wc2[k * 3 + c16] : 0.f);
            }
            s_wfrag[512 + ks * 64 + lane] = a;
            s_wfrag[640 + ks * 64 + lane] = c;
        }
    }
    if (tid < 96) {
        float v;
        if (tid < 64)      v = b1[tid];
        else if (tid < 80) v = b2[tid - 64];
        else               v = (tid - 80 < 3) ? bc2[tid - 80] : 0.f;
        s_bias[tid] = v;
    }

    // ---- per-ray setup ----
    float ox = rays_o[ray * 3 + 0], oy = rays_o[ray * 3 + 1], oz = rays_o[ray * 3 + 2];
    float dx = rays_d[ray * 3 + 0], dy = rays_d[ray * 3 + 1], dz = rays_d[ray * 3 + 2];
    float rn = rsqrtf(dx * dx + dy * dy + dz * dz);
    dx *= rn; dy *= rn; dz *= rn;

    float lo0 = aabb[0], lo1 = aabb[1], lo2 = aabb[2];
    float hi0 = aabb[3], hi1 = aabb[4], hi2 = aabb[5];

    float invx = 1.f / dx, invy = 1.f / dy, invz = 1.f / dz;
    float tx0 = (lo0 - ox) * invx, tx1 = (hi0 - ox) * invx;
    float ty0 = (lo1 - oy) * invy, ty1 = (hi1 - oy) * invy;
    float tz0 = (lo2 - oz) * invz, tz1 = (hi2 - oz) * invz;
    float tnear = fmaxf(fmaxf(fminf(tx0, tx1), fminf(ty0, ty1)), fminf(tz0, tz1));
    tnear = fmaxf(tnear, 0.f);
    float tfar = fminf(fminf(fmaxf(tx0, tx1), fmaxf(ty0, ty1)), fmaxf(tz0, tz1));
    tfar = fmaxf(tfar, tnear);
    float delta = (tfar - tnear) * (1.f / (float)NS);

    // dir constants for cin' rows 16..18 + bias row 19 (kg==2 k-slice)
    const u32 dir01 = pk2bf(dx, dy);
    const u32 dir2b = pk2bf(dz, 1.0f);

    // ---- coordinate phase: this wave, 2 samples per lane ----
#pragma unroll
    for (int i = 0; i < 2; ++i) {
        int s = i * 64 + lane;
        float t = tnear + delta * ((float)s + 0.5f);
        float px = ox + dx * t, py = oy + dy * t, pz = oz + dz * t;
        px = (px - lo0) * (2.f / (hi0 - lo0)) - 1.f;
        py = (py - lo1) * (2.f / (hi1 - lo1)) - 1.f;
        pz = (pz - lo2) * (2.f / (hi2 - lo2)) - 1.f;

        float p01[3], p02[3], p12[3];
        plane_interp(plane01, px, py, p01);
        plane_interp(plane02, px, pz, p02);
        plane_interp(plane12, py, pz, p12);
        float gx = p01[0] * p02[0] * p12[0];
        float gy = p01[1] * p02[1] * p12[1];
        float gz = p01[2] * p02[2] * p12[2];

        float qx = clampf((gx + 1.f) * (0.5f * 63.f), 0.f, 63.f);
        float qy = clampf((gy + 1.f) * (0.5f * 63.f), 0.f, 63.f);
        float qz = clampf((gz + 1.f) * (0.5f * 63.f), 0.f, 63.f);
        int ixg = (int)qx; if (ixg > 62) ixg = 62;
        int iyg = (int)qy; if (iyg > 62) iyg = 62;
        int izg = (int)qz; if (izg > 62) izg = 62;
        float fx = qx - (float)ixg, fy = qy - (float)iyg, fz = qz - (float)izg;
        float wx0 = 1.f - fx, wy0 = 1.f - fy, wz0 = 1.f - fz;
        u32x4 cw;
        cw[0] = pkh(wx0 * wy0 * wz0, wx0 * wy0 * fz);
        cw[1] = pkh(wx0 * fy  * wz0, wx0 * fy  * fz);
        cw[2] = pkh(fx  * wy0 * wz0, fx  * wy0 * fz);
        cw[3] = pkh(fx  * fy  * wz0, fx  * fy  * fz);
        s_cw[wv][s] = cw;
        s_fb[wv][s] = (u32)(ixg * 4096 + iyg * 64 + izg);
    }
    __syncthreads();   // weights + biases visible to all waves

    // relu C-regs, pack, b64-store to the swizzled [sample][dim] tile
#define RELUSTORE(ACC, NB) {                                           \
        u32x2 wr_;                                                     \
        wr_[0] = pk2bf(fmaxf((ACC)[0], 0.f), fmaxf((ACC)[1], 0.f));    \
        wr_[1] = pk2bf(fmaxf((ACC)[2], 0.f), fmaxf((ACC)[3], 0.f));    \
        *(u32x2*)&s_tile[wv][TSW(c16, (NB) * 16 + kg * 4)] = wr_; }

    // ---- 8 chunks of 16 samples ----
#pragma unroll 1
    for (int c = 0; c < 8; ++c) {
        u32x4 cwp = s_cw[wv][c * 16 + c16];
        u32 fb = s_fb[wv][c * 16 + c16];
        float2 w0p = uph(cwp[0]);
        float2 w1p = uph(cwp[1]);
        float2 w2p = uph(cwp[2]);
        float2 w3p = uph(cwp[3]);
        const float* fbase = features + fb;

        // gather + trilinear combine -> B-operand (col=sample, k=channel)
        u32x4 a1v;
#pragma unroll
        for (int jj = 0; jj < 4; ++jj) {
            float vv[2];
#pragma unroll
            for (int h = 0; h < 2; ++h) {
                const float* f = fbase + (size_t)(kg * 8 + jj * 2 + h) * 262144;
                f32x2u q0 = *(const f32x2u*)(f);
                f32x2u q1 = *(const f32x2u*)(f + 64);
                f32x2u q2 = *(const f32x2u*)(f + 4096);
                f32x2u q3 = *(const f32x2u*)(f + 4160);
                vv[h] = fmaf(w0p.x, q0[0], fmaf(w0p.y, q0[1],
                        fmaf(w1p.x, q1[0], fmaf(w1p.y, q1[1],
                        fmaf(w2p.x, q2[0], fmaf(w2p.y, q2[1],
                        fmaf(w3p.x, q3[0], w3p.y * q3[1])))))));
            }
            a1v[jj] = pk2bf(vv[0], vv[1]);
        }
        u16x8 a1 = __builtin_bit_cast(u16x8, a1v);

        // GEMM1 swapped: h^T = W1^T @ A1^T (weights + b1 C-init from LDS)
        f32x4 g0 = mfma_bf16(s_wfrag[0 * 64 + lane], a1, *(const f32x4*)&s_bias[0 * 16 + kg * 4]);
        f32x4 g1 = mfma_bf16(s_wfrag[1 * 64 + lane], a1, *(const f32x4*)&s_bias[1 * 16 + kg * 4]);
        f32x4 g2 = mfma_bf16(s_wfrag[2 * 64 + lane], a1, *(const f32x4*)&s_bias[2 * 16 + kg * 4]);
        f32x4 g3 = mfma_bf16(s_wfrag[3 * 64 + lane], a1, *(const f32x4*)&s_bias[3 * 16 + kg * 4]);

        RELUSTORE(g0, 0); RELUSTORE(g1, 1); RELUSTORE(g2, 2); RELUSTORE(g3, 3);
        u16x8 B2_0 = *(const u16x8*)&s_tile[wv][TSW(c16, kg * 8)];
        u16x8 B2_1 = *(const u16x8*)&s_tile[wv][TSW(c16, 32 + kg * 8)];

        // GEMM2 swapped: so^T = W2^T @ h^T
        f32x4 so = mfma_bf16(s_wfrag[512 + lane], B2_0, *(const f32x4*)&s_bias[64 + kg * 4]);
        so = mfma_bf16(s_wfrag[576 + lane], B2_1, so);

        // density (so row 0 -> kg==0, q==0 lanes)
        if (kg == 0) {
            float dens = __expf(clampf(so[0], -15.f, 15.f));
            s_tau[wv][c * 16 + c16] = dens * delta;
        }

        // cin'^T B-fragment via 4-lane shuffle; rows 16..18 = dir, 19 = 1.0
        u32 Q0 = pk2bf(so[0], so[1]);
        u32 Q1 = pk2bf(so[2], so[3]);
        u32x4 ct;
        ct[0] = (u32)__shfl((int)Q0, sA);
        ct[1] = (u32)__shfl((int)Q1, sA);
        ct[2] = (u32)__shfl((int)Q0, sB);
        ct[3] = (u32)__shfl((int)Q1, sB);
        if (kg == 2) { ct[0] = dir01; ct[1] = dir2b; ct[2] = 0u; ct[3] = 0u; }
        if (kg == 3) { ct[0] = 0u; ct[1] = 0u; ct[2] = 0u; ct[3] = 0u; }
        u16x8 bcin = __builtin_bit_cast(u16x8, ct);

        // GEMM3 swapped: h2^T = Wc1'^T @ cin'^T (bias via weight row 19)
        f32x4 zz; zz[0] = zz[1] = zz[2] = zz[3] = 0.f;
        f32x4 h0 = mfma_bf16(s_wfrag[256 + 0 * 64 + lane], bcin, zz);
        f32x4 h1 = mfma_bf16(s_wfrag[256 + 1 * 64 + lane], bcin, zz);
        f32x4 h2 = mfma_bf16(s_wfrag[256 + 2 * 64 + lane], bcin, zz);
        f32x4 h3 = mfma_bf16(s_wfrag[256 + 3 * 64 + lane], bcin, zz);

        RELUSTORE(h0, 0); RELUSTORE(h1, 1); RELUSTORE(h2, 2); RELUSTORE(h3, 3);
        u16x8 B4_0 = *(const u16x8*)&s_tile[wv][TSW(c16, kg * 8)];
        u16x8 B4_1 = *(const u16x8*)&s_tile[wv][TSW(c16, 32 + kg * 8)];

        // GEMM4 swapped: rgb^T = Wc2^T @ h2^T (bc2pad C-init from LDS)
        f32x4 cacc = mfma_bf16(s_wfrag[640 + lane], B4_0, *(const f32x4*)&s_bias[80 + kg * 4]);
        cacc = mfma_bf16(s_wfrag[704 + lane], B4_1, cacc);

        if (kg == 0) {
            int si = c * 16 + c16;
            s_rgb[wv][0][si] = 1.f / (1.f + __expf(-cacc[0]));
            s_rgb[wv][1][si] = 1.f / (1.f + __expf(-cacc[1]));
            s_rgb[wv][2][si] = 1.f / (1.f + __expf(-cacc[2]));
        }
    }
#undef RELUSTORE

    // ---- per-ray exponential integration (2 samples per lane) ----
    float t0 = s_tau[wv][lane];
    float t1 = s_tau[wv][64 + lane];
    float x0 = t0, x1 = t1;
#pragma unroll
    for (int off = 1; off < 64; off <<= 1) {
        float y = __shfl_up(x0, off);
        if (lane >= off) x0 += y;
    }
    float tot0 = __shfl(x0, 63);
#pragma unroll
    for (int off = 1; off < 64; off <<= 1) {
        float y = __shfl_up(x1, off);
        if (lane >= off) x1 += y;
    }
    x1 += tot0;

    float w0 = __expf(t0 - x0) * (1.f - __expf(-t0));
    float w1s = __expf(t1 - x1) * (1.f - __expf(-t1));

    float v0 = w0 * s_rgb[wv][0][lane] + w1s * s_rgb[wv][0][64 + lane];
    float v1 = w0 * s_rgb[wv][1][lane] + w1s * s_rgb[wv][1][64 + lane];
    float v2 = w0 * s_rgb[wv][2][lane] + w1s * s_rgb[wv][2][64 + lane];
    float v3 = w0 + w1s;
#pragma unroll
    for (int off = 32; off; off >>= 1) {
        v0 += __shfl_xor(v0, off);
        v1 += __shfl_xor(v1, off);
        v2 += __shfl_xor(v2, off);
        v3 += __shfl_xor(v3, off);
    }
    if (lane == 0) {
        float bg = bg_color[0];
        out[ray * 3 + 0] = v0 + (1.f - v3) * bg;
        out[ray * 3 + 1] = v1 + (1.f - v3) * bg;
        out[ray * 3 + 2] = v2 + (1.f - v3) * bg;
    }
}

extern "C" void kernel_launch(void* const* d_in, const int* in_sizes, int n_in,
                              void* d_out, int out_size, void* d_ws, size_t ws_size,
                              hipStream_t stream) {
    const float* rays_o  = (const float*)d_in[0];
    const float* rays_d  = (const float*)d_in[1];
    const float* bg      = (const float*)d_in[2];
    const float* p01     = (const float*)d_in[3];
    const float* p02     = (const float*)d_in[4];
    const float* p12     = (const float*)d_in[5];
    const float* feats   = (const float*)d_in[6];
    const float* w1      = (const float*)d_in[7];
    const float* b1      = (const float*)d_in[8];
    const float* w2      = (const float*)d_in[9];
    const float* b2      = (const float*)d_in[10];
    const float* wc1     = (const float*)d_in[11];
    const float* bc1     = (const float*)d_in[12];
    const float* wc2     = (const float*)d_in[13];
    const float* bc2     = (const float*)d_in[14];
    const float* aabb    = (const float*)d_in[15];
    float* out = (float*)d_out;

    const int use_ws = (ws_size >= 6144 * sizeof(u16)) ? 1 : 0;
    u16* wsb = (u16*)d_ws;
    if (use_ws) {
        prep_weights<<<24, 256, 0, stream>>>(w1, wc1, w2, wc2, bc1, wsb);
    }
    nerf_mfma<<<NRAYS / 4, 256, 0, stream>>>(rays_o, rays_d, bg, p01, p02, p12, feats,
                                             w1, b1, w2, b2, wc1, bc1, wc2, bc2, aabb, out,
                                             wsb, use_ws);
}

// Round 14
// 93.121 us; speedup vs baseline: 1.0841x; 1.0076x over previous
//
#include <hip/hip_runtime.h>

#define NS 128
#define NRAYS 8192

typedef unsigned short u16;
typedef unsigned int   u32;
typedef unsigned short u16x8 __attribute__((ext_vector_type(8)));
typedef __bf16 b16x8 __attribute__((ext_vector_type(8)));
typedef float f32x4 __attribute__((ext_vector_type(4)));
typedef _Float16 h16x2 __attribute__((ext_vector_type(2)));
typedef unsigned int u32x4 __attribute__((ext_vector_type(4)));
typedef unsigned int u32x2 __attribute__((ext_vector_type(2)));
typedef float f32x2u __attribute__((ext_vector_type(2), aligned(4)));

__device__ __forceinline__ float clampf(float x, float lo, float hi) {
    return fminf(fmaxf(x, lo), hi);
}

__device__ __forceinline__ u16 f2bf(float f) {
    return __builtin_bit_cast(u16, (__bf16)f);
}

// pack two f32 -> bf16 pair in one u32 (lo in bits 0-15)
__device__ __forceinline__ u32 pk2bf(float lo, float hi) {
    return (u32)f2bf(lo) | ((u32)f2bf(hi) << 16);
}

__device__ __forceinline__ u32 pkh(float a, float b) {
    h16x2 v; v[0] = (_Float16)a; v[1] = (_Float16)b;
    return __builtin_bit_cast(u32, v);
}
__device__ __forceinline__ float2 uph(u32 u) {
    h16x2 v = __builtin_bit_cast(h16x2, u);
    return make_float2((float)v[0], (float)v[1]);
}

__device__ __forceinline__ f32x4 mfma_bf16(u16x8 a, u16x8 b, f32x4 c) {
    return __builtin_amdgcn_mfma_f32_16x16x32_bf16(
        __builtin_bit_cast(b16x8, a), __builtin_bit_cast(b16x8, b), c, 0, 0, 0);
}

// swizzled u16-index into a [16][64] tile stored [sample][dim]
#define TSW(n, k) ((((n) * 64) + (k)) ^ (((n) & 7) << 3))

__device__ __forceinline__ void plane_interp(const float* __restrict__ g,
                                             float ca, float cb, float o[3]) {
    float pa = clampf((ca + 1.f) * (0.5f * 127.f), 0.f, 127.f);
    float pb = clampf((cb + 1.f) * (0.5f * 127.f), 0.f, 127.f);
    int la = (int)pa; if (la > 126) la = 126;
    int lb = (int)pb; if (lb > 126) lb = 126;
    float fa = pa - (float)la, fb = pb - (float)lb;
    const float* p = g + la * 128 + lb;
#pragma unroll
    for (int c = 0; c < 3; ++c) {
        const float* q = p + c * 16384;
        f32x2u q0 = *(const f32x2u*)q;
        f32x2u q1 = *(const f32x2u*)(q + 128);
        float top = fmaf(q0[1] - q0[0], fb, q0[0]);
        float bot = fmaf(q1[1] - q1[0], fb, q1[0]);
        o[c] = fmaf(bot - top, fa, top);
    }
}

// ---- prep: pack weight A-fragments (bf16, per-lane layout) into workspace ----
// AWc1' rows: [0]=0, [1..15]=wc1 so-rows, [16..18]=wc1 dir-rows, [19]=bc1 (bias
// row, pairs with cin' row19 == 1.0), [20..31]=0.
// layout (u16x8 units): [0,256) AW1 (nb*64+lane), [256,512) AWc1',
//                       [512,640) AW2 (ks*64+lane), [640,768) AWc2
__global__ __launch_bounds__(256)
void prep_weights(const float* __restrict__ w1, const float* __restrict__ wc1,
                  const float* __restrict__ w2, const float* __restrict__ wc2,
                  const float* __restrict__ bc1,
                  u16* __restrict__ wsb)
{
    int idx = blockIdx.x * 256 + threadIdx.x;   // 0..6143
    if (idx >= 6144) return;
    int lane = (idx >> 3) & 63;
    int j = idx & 7;
    int c16 = lane & 15, kg = lane >> 4;
    float v;
    if (idx < 2048) {                       // AW1
        int nb = idx >> 9;
        int k = kg * 8 + j;
        v = w1[k * 64 + nb * 16 + c16];
    } else if (idx < 4096) {                // AWc1' (permuted rows + bias row)
        int nb = (idx - 2048) >> 9;
        int k = kg * 8 + j;
        if (k == 0)       v = 0.f;
        else if (k < 16)  v = wc1[(k + 2) * 64 + nb * 16 + c16];
        else if (k < 19)  v = wc1[(k - 16) * 64 + nb * 16 + c16];
        else if (k == 19) v = bc1[nb * 16 + c16];
        else              v = 0.f;
    } else if (idx < 5120) {                // AW2
        int ks = (idx - 4096) >> 9;
        int k = ks * 32 + kg * 8 + j;
        v = w2[k * 16 + c16];
    } else {                                // AWc2 (M padded 3->16)
        int ks = (idx - 5120) >> 9;
        int k = ks * 32 + kg * 8 + j;
        v = (c16 < 3) ? wc2[k * 3 + c16] : 0.f;
    }
    wsb[idx] = f2bf(v);
}

// block = 4 rays, 4 waves, 1 wave = 1 ray, 8 chunks of 16 samples per wave.
// AW1/AWc1 in block-shared LDS; small AW2/AWc2 in VGPRs. rgb stored f16-packed.
// Gathers use uniform-base + u32 byte offsets (saddr form). LDS ~32.1 KB ->
// 5 blocks/CU occupancy cap.
__global__ __launch_bounds__(256)
void nerf_mfma(const float* __restrict__ rays_o,
               const float* __restrict__ rays_d,
               const float* __restrict__ bg_color,
               const float* __restrict__ plane01,
               const float* __restrict__ plane02,
               const float* __restrict__ plane12,
               const float* __restrict__ features,
               const float* __restrict__ w1, const float* __restrict__ b1,
               const float* __restrict__ w2, const float* __restrict__ b2,
               const float* __restrict__ wc1, const float* __restrict__ bc1,
               const float* __restrict__ wc2, const float* __restrict__ bc2,
               const float* __restrict__ aabb,
               float* __restrict__ out,
               const u16* __restrict__ wsb, int use_ws)
{
    __shared__ __align__(16) u16x8 s_wfrag[512];        // AW1 + AWc1' (8 KB)
    __shared__ __align__(16) float s_bias[96];          // b1[64], b2[16], bc2pad[16]
    __shared__ __align__(16) u32x4 s_cw[4][128];        // trilinear corner weights
    __shared__ u32   s_fb[4][128];                      // cell base BYTE offsets
    __shared__ __align__(16) u16  s_tile[4][16 * 64];   // per-wave transpose tile
    __shared__ float s_tau[4][128];
    __shared__ u32   s_rgbrg[4][128];                   // f16 pair (r,g)
    __shared__ u16   s_rgbb[4][128];                    // f16 b

    const int tid  = threadIdx.x;
    const int wv   = tid >> 6;
    const int lane = tid & 63;
    const int c16  = lane & 15;
    const int kg   = lane >> 4;
    const int ray  = blockIdx.x * 4 + wv;
    const int sA   = c16 + 16 * ((2 * kg) & 3);
    const int sB   = c16 + 16 * ((2 * kg + 1) & 3);

    // ---- stage AW1/AWc1 to LDS; AW2/AWc2 to VGPRs ----
    u16x8 AW2[2], AWc2[2];
    if (use_ws) {
        const u16x8* wf = (const u16x8*)wsb;
#pragma unroll
        for (int i = 0; i < 2; ++i) s_wfrag[tid + 256 * i] = wf[tid + 256 * i];
#pragma unroll
        for (int ks = 0; ks < 2; ++ks) {
            AW2[ks]  = wf[512 + ks * 64 + lane];
            AWc2[ks] = wf[640 + ks * 64 + lane];
        }
    } else {
        if (wv == 0) {
#pragma unroll
            for (int nb = 0; nb < 4; ++nb) {
                u16x8 a, c;
#pragma unroll
                for (int j = 0; j < 8; ++j) {
                    int k = kg * 8 + j;
                    a[j] = f2bf(w1[k * 64 + nb * 16 + c16]);
                    float v;
                    if (k == 0)       v = 0.f;
                    else if (k < 16)  v = wc1[(k + 2) * 64 + nb * 16 + c16];
                    else if (k < 19)  v = wc1[(k - 16) * 64 + nb * 16 + c16];
                    else if (k == 19) v = bc1[nb * 16 + c16];
                    else              v = 0.f;
                    c[j] = f2bf(v);
                }
                s_wfrag[nb * 64 + lane] = a;
                s_wfrag[256 + nb * 64 + lane] = c;
            }
        }
#pragma unroll
        for (int ks = 0; ks < 2; ++ks)
#pragma unroll
            for (int j = 0; j < 8; ++j) {
                int k = ks * 32 + kg * 8 + j;
                AW2[ks][j]  = f2bf(w2[k * 16 + c16]);
                AWc2[ks][j] = f2bf(c16 < 3 ? wc2[k * 3 + c16] : 0.f);
            }
    }
    if (tid < 96) {
        float v;
        if (tid < 64)      v = b1[tid];
        else if (tid < 80) v = b2[tid - 64];
        else               v = (tid - 80 < 3) ? bc2[tid - 80] : 0.f;
        s_bias[tid] = v;
    }

    // ---- per-ray setup ----
    float ox = rays_o[ray * 3 + 0], oy = rays_o[ray * 3 + 1], oz = rays_o[ray * 3 + 2];
    float dx = rays_d[ray * 3 + 0], dy = rays_d[ray * 3 + 1], dz = rays_d[ray * 3 + 2];
    float rn = rsqrtf(dx * dx + dy * dy + dz * dz);
    dx *= rn; dy *= rn; dz *= rn;

    float lo0 = aabb[0], lo1 = aabb[1], lo2 = aabb[2];
    float hi0 = aabb[3], hi1 = aabb[4], hi2 = aabb[5];

    float invx = 1.f / dx, invy = 1.f / dy, invz = 1.f / dz;
    float tx0 = (lo0 - ox) * invx, tx1 = (hi0 - ox) * invx;
    float ty0 = (lo1 - oy) * invy, ty1 = (hi1 - oy) * invy;
    float tz0 = (lo2 - oz) * invz, tz1 = (hi2 - oz) * invz;
    float tnear = fmaxf(fmaxf(fminf(tx0, tx1), fminf(ty0, ty1)), fminf(tz0, tz1));
    tnear = fmaxf(tnear, 0.f);
    float tfar = fminf(fminf(fmaxf(tx0, tx1), fmaxf(ty0, ty1)), fmaxf(tz0, tz1));
    tfar = fmaxf(tfar, tnear);
    float delta = (tfar - tnear) * (1.f / (float)NS);

    // dir constants for cin' rows 16..18 + bias row 19 (kg==2 k-slice)
    const u32 dir01 = pk2bf(dx, dy);
    const u32 dir2b = pk2bf(dz, 1.0f);

    // ---- coordinate phase: this wave, 2 samples per lane ----
#pragma unroll
    for (int i = 0; i < 2; ++i) {
        int s = i * 64 + lane;
        float t = tnear + delta * ((float)s + 0.5f);
        float px = ox + dx * t, py = oy + dy * t, pz = oz + dz * t;
        px = (px - lo0) * (2.f / (hi0 - lo0)) - 1.f;
        py = (py - lo1) * (2.f / (hi1 - lo1)) - 1.f;
        pz = (pz - lo2) * (2.f / (hi2 - lo2)) - 1.f;

        float p01[3], p02[3], p12[3];
        plane_interp(plane01, px, py, p01);
        plane_interp(plane02, px, pz, p02);
        plane_interp(plane12, py, pz, p12);
        float gx = p01[0] * p02[0] * p12[0];
        float gy = p01[1] * p02[1] * p12[1];
        float gz = p01[2] * p02[2] * p12[2];

        float qx = clampf((gx + 1.f) * (0.5f * 63.f), 0.f, 63.f);
        float qy = clampf((gy + 1.f) * (0.5f * 63.f), 0.f, 63.f);
        float qz = clampf((gz + 1.f) * (0.5f * 63.f), 0.f, 63.f);
        int ixg = (int)qx; if (ixg > 62) ixg = 62;
        int iyg = (int)qy; if (iyg > 62) iyg = 62;
        int izg = (int)qz; if (izg > 62) izg = 62;
        float fx = qx - (float)ixg, fy = qy - (float)iyg, fz = qz - (float)izg;
        float wx0 = 1.f - fx, wy0 = 1.f - fy, wz0 = 1.f - fz;
        u32x4 cw;
        cw[0] = pkh(wx0 * wy0 * wz0, wx0 * wy0 * fz);
        cw[1] = pkh(wx0 * fy  * wz0, wx0 * fy  * fz);
        cw[2] = pkh(fx  * wy0 * wz0, fx  * wy0 * fz);
        cw[3] = pkh(fx  * fy  * wz0, fx  * fy  * fz);
        s_cw[wv][s] = cw;
        // cell base as BYTE offset (u32): enables saddr-form gathers
        s_fb[wv][s] = (u32)(ixg * 4096 + iyg * 64 + izg) * 4u;
    }
    __syncthreads();   // weights + biases visible to all waves

    // relu C-regs, pack, b64-store to the swizzled [sample][dim] tile
#define RELUSTORE(ACC, NB) {                                           \
        u32x2 wr_;                                                     \
        wr_[0] = pk2bf(fmaxf((ACC)[0], 0.f), fmaxf((ACC)[1], 0.f));    \
        wr_[1] = pk2bf(fmaxf((ACC)[2], 0.f), fmaxf((ACC)[3], 0.f));    \
        *(u32x2*)&s_tile[wv][TSW(c16, (NB) * 16 + kg * 4)] = wr_; }

    const char* fby = (const char*)features;

    // ---- 8 chunks of 16 samples ----
#pragma unroll 1
    for (int c = 0; c < 8; ++c) {
        u32x4 cwp = s_cw[wv][c * 16 + c16];
        u32 fbB = s_fb[wv][c * 16 + c16];
        float2 w0p = uph(cwp[0]);
        float2 w1p = uph(cwp[1]);
        float2 w2p = uph(cwp[2]);
        float2 w3p = uph(cwp[3]);
        // this lane's channel-block base (byte offset): channel stride 1 MB
        u32 chb = fbB + (u32)(kg * 8) * 1048576u;

        // gather + trilinear combine -> B-operand (col=sample, k=channel)
        u32x4 a1v;
#pragma unroll
        for (int jj = 0; jj < 4; ++jj) {
            float vv[2];
#pragma unroll
            for (int h = 0; h < 2; ++h) {
                u32 off = chb + (u32)(jj * 2 + h) * 1048576u;
                f32x2u q0 = *(const f32x2u*)(fby + off);
                f32x2u q1 = *(const f32x2u*)(fby + off + 256);
                f32x2u q2 = *(const f32x2u*)(fby + off + 16384);
                f32x2u q3 = *(const f32x2u*)(fby + off + 16640);
                vv[h] = fmaf(w0p.x, q0[0], fmaf(w0p.y, q0[1],
                        fmaf(w1p.x, q1[0], fmaf(w1p.y, q1[1],
                        fmaf(w2p.x, q2[0], fmaf(w2p.y, q2[1],
                        fmaf(w3p.x, q3[0], w3p.y * q3[1])))))));
            }
            a1v[jj] = pk2bf(vv[0], vv[1]);
        }
        u16x8 a1 = __builtin_bit_cast(u16x8, a1v);

        // GEMM1 swapped: h^T = W1^T @ A1^T (weights + b1 C-init from LDS)
        f32x4 g0 = mfma_bf16(s_wfrag[0 * 64 + lane], a1, *(const f32x4*)&s_bias[0 * 16 + kg * 4]);
        f32x4 g1 = mfma_bf16(s_wfrag[1 * 64 + lane], a1, *(const f32x4*)&s_bias[1 * 16 + kg * 4]);
        f32x4 g2 = mfma_bf16(s_wfrag[2 * 64 + lane], a1, *(const f32x4*)&s_bias[2 * 16 + kg * 4]);
        f32x4 g3 = mfma_bf16(s_wfrag[3 * 64 + lane], a1, *(const f32x4*)&s_bias[3 * 16 + kg * 4]);

        RELUSTORE(g0, 0); RELUSTORE(g1, 1); RELUSTORE(g2, 2); RELUSTORE(g3, 3);
        u16x8 B2_0 = *(const u16x8*)&s_tile[wv][TSW(c16, kg * 8)];
        u16x8 B2_1 = *(const u16x8*)&s_tile[wv][TSW(c16, 32 + kg * 8)];

        // GEMM2 swapped: so^T = W2^T @ h^T
        f32x4 so = mfma_bf16(AW2[0], B2_0, *(const f32x4*)&s_bias[64 + kg * 4]);
        so = mfma_bf16(AW2[1], B2_1, so);

        // density (so row 0 -> kg==0, q==0 lanes)
        if (kg == 0) {
            float dens = __expf(clampf(so[0], -15.f, 15.f));
            s_tau[wv][c * 16 + c16] = dens * delta;
        }

        // cin'^T B-fragment via 4-lane shuffle; rows 16..18 = dir, 19 = 1.0
        u32 Q0 = pk2bf(so[0], so[1]);
        u32 Q1 = pk2bf(so[2], so[3]);
        u32x4 ct;
        ct[0] = (u32)__shfl((int)Q0, sA);
        ct[1] = (u32)__shfl((int)Q1, sA);
        ct[2] = (u32)__shfl((int)Q0, sB);
        ct[3] = (u32)__shfl((int)Q1, sB);
        if (kg == 2) { ct[0] = dir01; ct[1] = dir2b; ct[2] = 0u; ct[3] = 0u; }
        if (kg == 3) { ct[0] = 0u; ct[1] = 0u; ct[2] = 0u; ct[3] = 0u; }
        u16x8 bcin = __builtin_bit_cast(u16x8, ct);

        // GEMM3 swapped: h2^T = Wc1'^T @ cin'^T (bias via weight row 19)
        f32x4 zz; zz[0] = zz[1] = zz[2] = zz[3] = 0.f;
        f32x4 h0 = mfma_bf16(s_wfrag[256 + 0 * 64 + lane], bcin, zz);
        f32x4 h1 = mfma_bf16(s_wfrag[256 + 1 * 64 + lane], bcin, zz);
        f32x4 h2 = mfma_bf16(s_wfrag[256 + 2 * 64 + lane], bcin, zz);
        f32x4 h3 = mfma_bf16(s_wfrag[256 + 3 * 64 + lane], bcin, zz);

        RELUSTORE(h0, 0); RELUSTORE(h1, 1); RELUSTORE(h2, 2); RELUSTORE(h3, 3);
        u16x8 B4_0 = *(const u16x8*)&s_tile[wv][TSW(c16, kg * 8)];
        u16x8 B4_1 = *(const u16x8*)&s_tile[wv][TSW(c16, 32 + kg * 8)];

        // GEMM4 swapped: rgb^T = Wc2^T @ h2^T (bc2pad C-init from LDS)
        f32x4 cacc = mfma_bf16(AWc2[0], B4_0, *(const f32x4*)&s_bias[80 + kg * 4]);
        cacc = mfma_bf16(AWc2[1], B4_1, cacc);

        if (kg == 0) {
            int si = c * 16 + c16;
            float r = 1.f / (1.f + __expf(-cacc[0]));
            float g = 1.f / (1.f + __expf(-cacc[1]));
            float b = 1.f / (1.f + __expf(-cacc[2]));
            s_rgbrg[wv][si] = pkh(r, g);
            s_rgbb[wv][si] = (u16)(pkh(b, 0.f) & 0xffffu);
        }
    }
#undef RELUSTORE

    // ---- per-ray exponential integration (2 samples per lane) ----
    float t0 = s_tau[wv][lane];
    float t1 = s_tau[wv][64 + lane];
    float x0 = t0, x1 = t1;
#pragma unroll
    for (int off = 1; off < 64; off <<= 1) {
        float y = __shfl_up(x0, off);
        if (lane >= off) x0 += y;
    }
    float tot0 = __shfl(x0, 63);
#pragma unroll
    for (int off = 1; off < 64; off <<= 1) {
        float y = __shfl_up(x1, off);
        if (lane >= off) x1 += y;
    }
    x1 += tot0;

    float w0 = __expf(t0 - x0) * (1.f - __expf(-t0));
    float w1s = __expf(t1 - x1) * (1.f - __expf(-t1));

    float2 rg0 = uph(s_rgbrg[wv][lane]);
    float2 rg1 = uph(s_rgbrg[wv][64 + lane]);
    float bb0 = uph((u32)s_rgbb[wv][lane]).x;
    float bb1 = uph((u32)s_rgbb[wv][64 + lane]).x;

    float v0 = w0 * rg0.x + w1s * rg1.x;
    float v1 = w0 * rg0.y + w1s * rg1.y;
    float v2 = w0 * bb0 + w1s * bb1;
    float v3 = w0 + w1s;
#pragma unroll
    for (int off = 32; off; off >>= 1) {
        v0 += __shfl_xor(v0, off);
        v1 += __shfl_xor(v1, off);
        v2 += __shfl_xor(v2, off);
        v3 += __shfl_xor(v3, off);
    }
    if (lane == 0) {
        float bg = bg_color[0];
        out[ray * 3 + 0] = v0 + (1.f - v3) * bg;
        out[ray * 3 + 1] = v1 + (1.f - v3) * bg;
        out[ray * 3 + 2] = v2 + (1.f - v3) * bg;
    }
}

extern "C" void kernel_launch(void* const* d_in, const int* in_sizes, int n_in,
                              void* d_out, int out_size, void* d_ws, size_t ws_size,
                              hipStream_t stream) {
    const float* rays_o  = (const float*)d_in[0];
    const float* rays_d  = (const float*)d_in[1];
    const float* bg      = (const float*)d_in[2];
    const float* p01     = (const float*)d_in[3];
    const float* p02     = (const float*)d_in[4];
    const float* p12     = (const float*)d_in[5];
    const float* feats   = (const float*)d_in[6];
    const float* w1      = (const float*)d_in[7];
    const float* b1      = (const float*)d_in[8];
    const float* w2      = (const float*)d_in[9];
    const float* b2      = (const float*)d_in[10];
    const float* wc1     = (const float*)d_in[11];
    const float* bc1     = (const float*)d_in[12];
    const float* wc2     = (const float*)d_in[13];
    const float* bc2     = (const float*)d_in[14];
    const float* aabb    = (const float*)d_in[15];
    float* out = (float*)d_out;

    const int use_ws = (ws_size >= 6144 * sizeof(u16)) ? 1 : 0;
    u16* wsb = (u16*)d_ws;
    if (use_ws) {
        prep_weights<<<24, 256, 0, stream>>>(w1, wc1, w2, wc2, bc1, wsb);
    }
    nerf_mfma<<<NRAYS / 4, 256, 0, stream>>>(rays_o, rays_d, bg, p01, p02, p12, feats,
                                             w1, b1, w2, b2, wc1, bc1, wc2, bc2, aabb, out,
                                             wsb, use_ws);
}